// Round 2
// baseline (180.197 us; speedup 1.0000x reference)
//
#include <hip/hip_runtime.h>
#include <hip/hip_cooperative_groups.h>

namespace cg = cooperative_groups;

// 6-layer MLP (1->64, 4x 64->64, 64->1), N=2,097,152 rows, fp32 in/out.
// R15 = R14 with the nontemporal-store compile fix (native clang vector
// type instead of HIP_vector_type). Structure:
//  - ONE cooperative kernel: blocks 0..64 build the table slice (bitwise
//    identical to R13's K1); ALL 512 blocks prefetch their gather float4s
//    into registers BEFORE grid.sync() (8 MB x-read hides under build);
//    grid.sync() replaces the kernel boundary; non-temporal out stores.
// Co-residency: __launch_bounds__(512,4) caps VGPR<=128 -> 2 blocks/CU;
// LDS 34.5KB <= 80KB -> 512 blocks on 256 CUs.
// Fallback: R13's two-kernel path if hipLaunchCooperativeKernel refuses;
// mlp_direct if ws too small (never in practice).

typedef short short8 __attribute__((ext_vector_type(8)));
typedef float float16 __attribute__((ext_vector_type(16)));
typedef float vfloat4 __attribute__((ext_vector_type(4)));   // native vec4

// A-fragment strides in SHORTS: [L][s][m][lane][t]  (single bf16 part)
#define T_STRIDE    8
#define M_STRIDE    (64 * T_STRIDE)          // 512
#define S_STRIDE    (2 * M_STRIDE)           // 1024
#define L_STRIDE    (4 * S_STRIDE)           // 4096
#define A_TOTAL     (4 * L_STRIDE)           // 16384 shorts = 32768 B

#define NINTERV     16384                    // 2^14 intervals
#define NBUILD      65                       // 65*256 = 16640 nodes >= NINTERV+1
#define NNODES      (NBUILD * 256)
#define WS_NEEDED   (NNODES * 4)

#define XMIN        (-9.0f)
#define DELTA       0.0010986328125f         // 18/16384 = 9*2^-13, exact
#define INVD        (16384.0f / 18.0f)

#define FUSED_BLOCKS 512
#define FUSED_THREADS 512

#define LOG2E 1.44269504088896340736f
#define LN2   0.69314718055994530942f

union FRAG { int4 i; short8 s; };

__device__ __forceinline__ float silu_l2(float a) {
    float e = __builtin_amdgcn_exp2f(-a);
    return a * __builtin_amdgcn_rcpf(1.0f + e);
}

__device__ __forceinline__ unsigned pack_pair(float h0, float h1) {
    return __builtin_amdgcn_perm(__builtin_bit_cast(unsigned, h1),
                                 __builtin_bit_cast(unsigned, h0), 0x07060302u);
}

__device__ __forceinline__ unsigned short bf16_rtne(float v) {
    unsigned u = __builtin_bit_cast(unsigned, v);
    unsigned r = (u + 0x7FFFu + ((u >> 16) & 1u)) >> 16;
    return (unsigned short)r;
}

// Self-prep: build the LDS weight image + bias/Wout tables from global
// weights. 512 threads; caller must __syncthreads() after.
__device__ __forceinline__ void self_prep(
    const float* __restrict__ W0, const float* __restrict__ b0,
    const float* __restrict__ W1, const float* __restrict__ W2,
    const float* __restrict__ W3, const float* __restrict__ W4,
    const float* __restrict__ b1, const float* __restrict__ b2,
    const float* __restrict__ b3, const float* __restrict__ b4,
    const float* __restrict__ Wout,
    unsigned short* ldsA, float* sPB, float* sPW, float* sPW0, float* sPB0,
    int tid)
{
    const float* Ws[4] = {W1, W2, W3, W4};
    const float* bs[4] = {b1, b2, b3, b4};

    for (int i = tid; i < 4 * 4 * 2 * 64; i += 512) {
        int L = i >> 9, s = (i >> 7) & 3, m = (i >> 6) & 1, lane = i & 63;
        int h = lane >> 5;
        int nn = m * 32 + (lane & 31);
        const float* W = Ws[L];
        unsigned short* d = ldsA + L * L_STRIDE + s * S_STRIDE + m * M_STRIDE
                                 + lane * T_STRIDE;
        for (int t = 0; t < 8; ++t) {
            int k = s * 16 + h * 8 + t;
            int col = (L == 0) ? k : ((k & ~12) | ((k & 4) << 1) | ((k & 8) >> 1));
            d[t] = bf16_rtne(W[nn * 64 + col]);
        }
    }
    if (tid < 256) {
        int L = tid >> 6, h = (tid >> 5) & 1, m = (tid >> 4) & 1, r = tid & 15;
        int nu = 32 * m + (r & 3) + 8 * (r >> 2) + 4 * h;
        sPB[tid] = bs[L][nu] * LOG2E;
    }
    if (tid < 64) {
        int h = (tid >> 5) & 1, m = (tid >> 4) & 1, r = tid & 15;
        int nu = 32 * m + (r & 3) + 8 * (r >> 2) + 4 * h;
        sPW[tid]  = Wout[nu] * LN2;
        sPW0[tid] = W0[tid] * LOG2E;
        sPB0[tid] = b0[tid] * LOG2E;
    }
}

// Core MLP eval for one lane-row value xv -> f(xv). Shared by build/direct.
__device__ __forceinline__ float mlp_eval(
    float xv, int lane, int h,
    const unsigned short* ldsA, const float* sPB, const float* sPW,
    const float* sPW0, const float* sPB0, float bout0)
{
    FRAG B[4];
#pragma unroll
    for (int s = 0; s < 4; ++s) {
        float w0t[8], b0t[8];
        *(float4*)&w0t[0] = *(const float4*)(sPW0 + s * 16 + h * 8);
        *(float4*)&w0t[4] = *(const float4*)(sPW0 + s * 16 + h * 8 + 4);
        *(float4*)&b0t[0] = *(const float4*)(sPB0 + s * 16 + h * 8);
        *(float4*)&b0t[4] = *(const float4*)(sPB0 + s * 16 + h * 8 + 4);
#pragma unroll
        for (int j = 0; j < 4; ++j) {
            float a0 = silu_l2(fmaf(xv, w0t[2 * j], b0t[2 * j]));
            float a1 = silu_l2(fmaf(xv, w0t[2 * j + 1], b0t[2 * j + 1]));
            B[s].i[j] = (int)pack_pair(a0, a1);
        }
    }

    float16 acc[2];
    float result = 0.0f;
#pragma unroll
    for (int L = 0; L < 4; ++L) {
        const float* pb0 = sPB + ((L * 2 + h) * 2 + 0) * 16;
        const float* pb1 = sPB + ((L * 2 + h) * 2 + 1) * 16;
#pragma unroll
        for (int r = 0; r < 16; ++r) {
            acc[0][r] = pb0[r];
            acc[1][r] = pb1[r];
        }
        const unsigned short* aL = ldsA + L * L_STRIDE;
#pragma unroll
        for (int s = 0; s < 4; ++s) {
            const unsigned short* base = aL + s * S_STRIDE + lane * T_STRIDE;
            short8 a0 = *(const short8*)(base + 0 * M_STRIDE);
            short8 a1 = *(const short8*)(base + 1 * M_STRIDE);
            acc[0] = __builtin_amdgcn_mfma_f32_32x32x16_bf16(a0, B[s].s, acc[0], 0, 0, 0);
            acc[1] = __builtin_amdgcn_mfma_f32_32x32x16_bf16(a1, B[s].s, acc[1], 0, 0, 0);
        }
        if (L < 3) {
#pragma unroll
            for (int s2 = 0; s2 < 4; ++s2) {
                const int m = s2 >> 1;
                const int rb = 8 * (s2 & 1);
#pragma unroll
                for (int j = 0; j < 4; ++j) {
                    float h0 = silu_l2(acc[m][rb + 2 * j]);
                    float h1 = silu_l2(acc[m][rb + 2 * j + 1]);
                    B[s2].i[j] = (int)pack_pair(h0, h1);
                }
            }
        } else {
            const float* pw0 = sPW + (h * 2 + 0) * 16;
            const float* pw1 = sPW + (h * 2 + 1) * 16;
            float dot = 0.0f;
#pragma unroll
            for (int r = 0; r < 16; ++r) {
                dot = fmaf(silu_l2(acc[0][r]), pw0[r], dot);
                dot = fmaf(silu_l2(acc[1][r]), pw1[r], dot);
            }
            dot += __shfl_xor(dot, 32);
            result = dot + bout0;
        }
    }
    return result;
}

// ---------------- gather helper -------------------------------------------
__device__ __forceinline__ float lerp1(float xc, const float* __restrict__ T) {
    float t = (xc - XMIN) * INVD;
    float kf = fminf(fmaxf(floorf(t), 0.0f), (float)(NINTERV - 1));
    int k = (int)kf;
    float node = fmaf(kf, DELTA, XMIN);          // bitwise == build's x_k
    float frac = (xc - node) * INVD;
    float t0 = T[k], t1 = T[k + 1];
    return fmaf(frac, t1 - t0, t0);
}

__device__ __forceinline__ vfloat4 lerp4v(float4 v, const float* __restrict__ T) {
    vfloat4 r;
    r.x = lerp1(v.x, T);
    r.y = lerp1(v.y, T);
    r.z = lerp1(v.z, T);
    r.w = lerp1(v.w, T);
    return r;
}

// ---------------- fused: build (blocks 0..64) + grid.sync + gather --------
__global__ __launch_bounds__(FUSED_THREADS, 4) void fused_mlp(
    const float* __restrict__ x,
    const float* __restrict__ W0, const float* __restrict__ b0,
    const float* __restrict__ W1, const float* __restrict__ W2,
    const float* __restrict__ W3, const float* __restrict__ W4,
    const float* __restrict__ b1, const float* __restrict__ b2,
    const float* __restrict__ b3, const float* __restrict__ b4,
    const float* __restrict__ Wout, const float* __restrict__ bout,
    float* __restrict__ tab, float* __restrict__ out, int n)
{
    __shared__ unsigned short ldsA[A_TOTAL];
    __shared__ __align__(16) float sPB[256];
    __shared__ __align__(16) float sPW[64];
    __shared__ __align__(16) float sPW0[64];
    __shared__ __align__(16) float sPB0[64];

    const int tid = threadIdx.x;
    const int bid = blockIdx.x;

    if (bid < NBUILD) {
        self_prep(W0, b0, W1, W2, W3, W4, b1, b2, b3, b4, Wout,
                  ldsA, sPB, sPW, sPW0, sPB0, tid);
        __syncthreads();
        const int lane = tid & 63;
        const int wv = tid >> 6;
        const int h = lane >> 5;
        const int lr = lane & 31;
        const int krow = bid * 256 + wv * 32 + lr;   // node < NNODES
        const float xv = fmaf((float)krow, DELTA, XMIN);
        float r = mlp_eval(xv, lane, h, ldsA, sPB, sPW, sPW0, sPB0, bout[0]);
        if (h == 0) tab[krow] = r;
    }

    // Prefetch this thread's gather operands into registers BEFORE the grid
    // barrier: the 8 MB x-read rides under the table build / sync wait.
    const int TT = FUSED_BLOCKS * FUSED_THREADS;     // 262144 threads
    const int gtid = bid * FUSED_THREADS + tid;
    const int n4 = n >> 2;                           // 524288 float4s
    const float4* __restrict__ x4 = (const float4*)x;
    vfloat4* __restrict__ o4 = (vfloat4*)out;

    float4 v0, v1;
    const bool has0 = gtid < n4;
    const bool has1 = gtid + TT < n4;
    if (has0) v0 = x4[gtid];
    if (has1) v1 = x4[gtid + TT];

    cg::this_grid().sync();   // table complete + device-visible

    if (has0) __builtin_nontemporal_store(lerp4v(v0, tab), o4 + gtid);
    if (has1) __builtin_nontemporal_store(lerp4v(v1, tab), o4 + gtid + TT);
    // generic leftover (n4 > 2*TT never happens at N=2^21, kept for safety)
    for (int i = gtid + 2 * TT; i < n4; i += TT)
        __builtin_nontemporal_store(lerp4v(x4[i], tab), o4 + i);
    if (gtid == 0) {                                 // scalar tail (n % 4)
        for (int j = n & ~3; j < n; ++j) out[j] = lerp1(x[j], tab);
    }
}

// ---------------- K1: build table (fallback path) -------------------------
__global__ __launch_bounds__(512, 4) void build_table(
    const float* __restrict__ W0, const float* __restrict__ b0,
    const float* __restrict__ W1, const float* __restrict__ W2,
    const float* __restrict__ W3, const float* __restrict__ W4,
    const float* __restrict__ b1, const float* __restrict__ b2,
    const float* __restrict__ b3, const float* __restrict__ b4,
    const float* __restrict__ Wout, const float* __restrict__ bout,
    float* __restrict__ tab)
{
    __shared__ unsigned short ldsA[A_TOTAL];
    __shared__ __align__(16) float sPB[256];
    __shared__ __align__(16) float sPW[64];
    __shared__ __align__(16) float sPW0[64];
    __shared__ __align__(16) float sPB0[64];

    const int tid = threadIdx.x;
    self_prep(W0, b0, W1, W2, W3, W4, b1, b2, b3, b4, Wout,
              ldsA, sPB, sPW, sPW0, sPB0, tid);
    __syncthreads();

    const int lane = tid & 63;
    const int wv = tid >> 6;
    const int h = lane >> 5;
    const int lr = lane & 31;
    const int krow = blockIdx.x * 256 + wv * 32 + lr;   // node < NNODES

    const float xv = fmaf((float)krow, DELTA, XMIN);
    float r = mlp_eval(xv, lane, h, ldsA, sPB, sPW, sPW0, sPB0, bout[0]);
    if (h == 0) tab[krow] = r;
}

// ---------------- K2: gather / lerp (fallback path) -----------------------
__global__ __launch_bounds__(256) void gather_lerp(
    const float* __restrict__ x, const float* __restrict__ T,
    float* __restrict__ out, int n)
{
    int i = blockIdx.x * 256 + threadIdx.x;
    int n4 = n >> 2;
    if (i < n4) {
        float4 v = ((const float4*)x)[i];
        float4 r;
        r.x = lerp1(v.x, T);
        r.y = lerp1(v.y, T);
        r.z = lerp1(v.z, T);
        r.w = lerp1(v.w, T);
        ((float4*)out)[i] = r;
    }
    if (blockIdx.x == 0 && threadIdx.x == 0) {   // scalar tail (n % 4)
        for (int j = n & ~3; j < n; ++j) out[j] = lerp1(x[j], T);
    }
}

// ---------------- fallback: direct per-row (ws too small; never expected) --
__global__ __launch_bounds__(512, 4) void mlp_direct(
    const float* __restrict__ x,
    const float* __restrict__ W0, const float* __restrict__ b0,
    const float* __restrict__ W1, const float* __restrict__ W2,
    const float* __restrict__ W3, const float* __restrict__ W4,
    const float* __restrict__ b1, const float* __restrict__ b2,
    const float* __restrict__ b3, const float* __restrict__ b4,
    const float* __restrict__ Wout, const float* __restrict__ bout,
    float* __restrict__ out, int n)
{
    __shared__ unsigned short ldsA[A_TOTAL];
    __shared__ __align__(16) float sPB[256];
    __shared__ __align__(16) float sPW[64];
    __shared__ __align__(16) float sPW0[64];
    __shared__ __align__(16) float sPB0[64];

    const int tid = threadIdx.x;
    self_prep(W0, b0, W1, W2, W3, W4, b1, b2, b3, b4, Wout,
              ldsA, sPB, sPW, sPW0, sPB0, tid);
    __syncthreads();

    const int lane = tid & 63;
    const int wv = tid >> 6;
    const int h = lane >> 5;
    const int lr = lane & 31;
    const int row = blockIdx.x * 256 + wv * 32 + lr;
    const float xv = (row < n) ? x[row] : 0.0f;

    float r = mlp_eval(xv, lane, h, ldsA, sPB, sPW, sPW0, sPB0, bout[0]);
    if (h == 0 && row < n) out[row] = r;
}

extern "C" void kernel_launch(void* const* d_in, const int* in_sizes, int n_in,
                              void* d_out, int out_size, void* d_ws, size_t ws_size,
                              hipStream_t stream) {
    const float* x    = (const float*)d_in[0];
    const float* W0   = (const float*)d_in[1];
    const float* b0   = (const float*)d_in[2];
    const float* W1   = (const float*)d_in[3];
    const float* b1   = (const float*)d_in[4];
    const float* W2   = (const float*)d_in[5];
    const float* b2   = (const float*)d_in[6];
    const float* W3   = (const float*)d_in[7];
    const float* b3   = (const float*)d_in[8];
    const float* W4   = (const float*)d_in[9];
    const float* b4   = (const float*)d_in[10];
    const float* Wout = (const float*)d_in[11];
    const float* bout = (const float*)d_in[12];
    float* out = (float*)d_out;

    int n = in_sizes[0];  // 2,097,152

    if (ws_size >= (size_t)WS_NEEDED) {
        float* tab = (float*)d_ws;
        void* args[] = {
            (void*)&x,
            (void*)&W0, (void*)&b0,
            (void*)&W1, (void*)&W2, (void*)&W3, (void*)&W4,
            (void*)&b1, (void*)&b2, (void*)&b3, (void*)&b4,
            (void*)&Wout, (void*)&bout,
            (void*)&tab, (void*)&out, (void*)&n
        };
        hipError_t ce = hipLaunchCooperativeKernel(
            (const void*)fused_mlp, dim3(FUSED_BLOCKS), dim3(FUSED_THREADS),
            args, 0u, stream);
        if (ce != hipSuccess) {
            (void)hipGetLastError();   // clear; fall back to proven 2-kernel path
            build_table<<<NBUILD, 512, 0, stream>>>(W0, b0, W1, W2, W3, W4,
                                                    b1, b2, b3, b4, Wout, bout, tab);
            int gblocks = (n / 4 + 255) / 256;
            gather_lerp<<<gblocks, 256, 0, stream>>>(x, tab, out, n);
        }
    } else {
        mlp_direct<<<(n + 255) / 256, 512, 0, stream>>>(x, W0, b0, W1, W2, W3,
                                                        W4, b1, b2, b3, b4,
                                                        Wout, bout, out, n);
    }
}

// Round 3
// 99.299 us; speedup vs baseline: 1.8147x; 1.8147x over previous
//
#include <hip/hip_runtime.h>

// 6-layer MLP (1->64, 4x 64->64, 64->1), N=2,097,152 rows, fp32 in/out.
// R16 = revert to R13's proven two-kernel structure (99.6 us measured).
// R14/R15's cooperative fusion REGRESSED to 180 us: cg::this_grid().sync()
// cost ~60 us (device-scope L2 writeback/invalidate across 8 XCDs x 512
// blocks; kernel sat at 2.7% VALUBusy). Fusion via manual flag+spin needs
// the same cache maintenance -> dead end, measured.
// Only change vs R13: non-temporal float4 stores for `out` in gather
// (write-once stream; keep L2/L3 for x + table).
// Pipeline: K1 build (65 blocks, self-prep + MLP at 16640 nodes)
//           K2 gather (out[i] = lerp(table, x[i]))
// Fallback (ws < 66 KB, never in practice): direct per-row kernel.

typedef short short8 __attribute__((ext_vector_type(8)));
typedef float float16 __attribute__((ext_vector_type(16)));
typedef float vfloat4 __attribute__((ext_vector_type(4)));   // native vec4

// A-fragment strides in SHORTS: [L][s][m][lane][t]  (single bf16 part)
#define T_STRIDE    8
#define M_STRIDE    (64 * T_STRIDE)          // 512
#define S_STRIDE    (2 * M_STRIDE)           // 1024
#define L_STRIDE    (4 * S_STRIDE)           // 4096
#define A_TOTAL     (4 * L_STRIDE)           // 16384 shorts = 32768 B

#define NINTERV     16384                    // 2^14 intervals
#define NBUILD      65                       // 65*256 = 16640 nodes >= NINTERV+1
#define NNODES      (NBUILD * 256)
#define WS_NEEDED   (NNODES * 4)

#define XMIN        (-9.0f)
#define DELTA       0.0010986328125f         // 18/16384 = 9*2^-13, exact
#define INVD        (16384.0f / 18.0f)

#define LOG2E 1.44269504088896340736f
#define LN2   0.69314718055994530942f

union FRAG { int4 i; short8 s; };

__device__ __forceinline__ float silu_l2(float a) {
    float e = __builtin_amdgcn_exp2f(-a);
    return a * __builtin_amdgcn_rcpf(1.0f + e);
}

__device__ __forceinline__ unsigned pack_pair(float h0, float h1) {
    return __builtin_amdgcn_perm(__builtin_bit_cast(unsigned, h1),
                                 __builtin_bit_cast(unsigned, h0), 0x07060302u);
}

__device__ __forceinline__ unsigned short bf16_rtne(float v) {
    unsigned u = __builtin_bit_cast(unsigned, v);
    unsigned r = (u + 0x7FFFu + ((u >> 16) & 1u)) >> 16;
    return (unsigned short)r;
}

// Self-prep: build the LDS weight image + bias/Wout tables from global
// weights. 512 threads; caller must __syncthreads() after.
__device__ __forceinline__ void self_prep(
    const float* __restrict__ W0, const float* __restrict__ b0,
    const float* __restrict__ W1, const float* __restrict__ W2,
    const float* __restrict__ W3, const float* __restrict__ W4,
    const float* __restrict__ b1, const float* __restrict__ b2,
    const float* __restrict__ b3, const float* __restrict__ b4,
    const float* __restrict__ Wout,
    unsigned short* ldsA, float* sPB, float* sPW, float* sPW0, float* sPB0,
    int tid)
{
    const float* Ws[4] = {W1, W2, W3, W4};
    const float* bs[4] = {b1, b2, b3, b4};

    for (int i = tid; i < 4 * 4 * 2 * 64; i += 512) {
        int L = i >> 9, s = (i >> 7) & 3, m = (i >> 6) & 1, lane = i & 63;
        int h = lane >> 5;
        int nn = m * 32 + (lane & 31);
        const float* W = Ws[L];
        unsigned short* d = ldsA + L * L_STRIDE + s * S_STRIDE + m * M_STRIDE
                                 + lane * T_STRIDE;
        for (int t = 0; t < 8; ++t) {
            int k = s * 16 + h * 8 + t;
            int col = (L == 0) ? k : ((k & ~12) | ((k & 4) << 1) | ((k & 8) >> 1));
            d[t] = bf16_rtne(W[nn * 64 + col]);
        }
    }
    if (tid < 256) {
        int L = tid >> 6, h = (tid >> 5) & 1, m = (tid >> 4) & 1, r = tid & 15;
        int nu = 32 * m + (r & 3) + 8 * (r >> 2) + 4 * h;
        sPB[tid] = bs[L][nu] * LOG2E;
    }
    if (tid < 64) {
        int h = (tid >> 5) & 1, m = (tid >> 4) & 1, r = tid & 15;
        int nu = 32 * m + (r & 3) + 8 * (r >> 2) + 4 * h;
        sPW[tid]  = Wout[nu] * LN2;
        sPW0[tid] = W0[tid] * LOG2E;
        sPB0[tid] = b0[tid] * LOG2E;
    }
}

// Core MLP eval for one lane-row value xv -> f(xv). Shared by build/direct.
__device__ __forceinline__ float mlp_eval(
    float xv, int lane, int h,
    const unsigned short* ldsA, const float* sPB, const float* sPW,
    const float* sPW0, const float* sPB0, float bout0)
{
    FRAG B[4];
#pragma unroll
    for (int s = 0; s < 4; ++s) {
        float w0t[8], b0t[8];
        *(float4*)&w0t[0] = *(const float4*)(sPW0 + s * 16 + h * 8);
        *(float4*)&w0t[4] = *(const float4*)(sPW0 + s * 16 + h * 8 + 4);
        *(float4*)&b0t[0] = *(const float4*)(sPB0 + s * 16 + h * 8);
        *(float4*)&b0t[4] = *(const float4*)(sPB0 + s * 16 + h * 8 + 4);
#pragma unroll
        for (int j = 0; j < 4; ++j) {
            float a0 = silu_l2(fmaf(xv, w0t[2 * j], b0t[2 * j]));
            float a1 = silu_l2(fmaf(xv, w0t[2 * j + 1], b0t[2 * j + 1]));
            B[s].i[j] = (int)pack_pair(a0, a1);
        }
    }

    float16 acc[2];
    float result = 0.0f;
#pragma unroll
    for (int L = 0; L < 4; ++L) {
        const float* pb0 = sPB + ((L * 2 + h) * 2 + 0) * 16;
        const float* pb1 = sPB + ((L * 2 + h) * 2 + 1) * 16;
#pragma unroll
        for (int r = 0; r < 16; ++r) {
            acc[0][r] = pb0[r];
            acc[1][r] = pb1[r];
        }
        const unsigned short* aL = ldsA + L * L_STRIDE;
#pragma unroll
        for (int s = 0; s < 4; ++s) {
            const unsigned short* base = aL + s * S_STRIDE + lane * T_STRIDE;
            short8 a0 = *(const short8*)(base + 0 * M_STRIDE);
            short8 a1 = *(const short8*)(base + 1 * M_STRIDE);
            acc[0] = __builtin_amdgcn_mfma_f32_32x32x16_bf16(a0, B[s].s, acc[0], 0, 0, 0);
            acc[1] = __builtin_amdgcn_mfma_f32_32x32x16_bf16(a1, B[s].s, acc[1], 0, 0, 0);
        }
        if (L < 3) {
#pragma unroll
            for (int s2 = 0; s2 < 4; ++s2) {
                const int m = s2 >> 1;
                const int rb = 8 * (s2 & 1);
#pragma unroll
                for (int j = 0; j < 4; ++j) {
                    float h0 = silu_l2(acc[m][rb + 2 * j]);
                    float h1 = silu_l2(acc[m][rb + 2 * j + 1]);
                    B[s2].i[j] = (int)pack_pair(h0, h1);
                }
            }
        } else {
            const float* pw0 = sPW + (h * 2 + 0) * 16;
            const float* pw1 = sPW + (h * 2 + 1) * 16;
            float dot = 0.0f;
#pragma unroll
            for (int r = 0; r < 16; ++r) {
                dot = fmaf(silu_l2(acc[0][r]), pw0[r], dot);
                dot = fmaf(silu_l2(acc[1][r]), pw1[r], dot);
            }
            dot += __shfl_xor(dot, 32);
            result = dot + bout0;
        }
    }
    return result;
}

// ---------------- K1: build table (self-prep, static range) ---------------
__global__ __launch_bounds__(512, 4) void build_table(
    const float* __restrict__ W0, const float* __restrict__ b0,
    const float* __restrict__ W1, const float* __restrict__ W2,
    const float* __restrict__ W3, const float* __restrict__ W4,
    const float* __restrict__ b1, const float* __restrict__ b2,
    const float* __restrict__ b3, const float* __restrict__ b4,
    const float* __restrict__ Wout, const float* __restrict__ bout,
    float* __restrict__ tab)
{
    __shared__ unsigned short ldsA[A_TOTAL];
    __shared__ __align__(16) float sPB[256];
    __shared__ __align__(16) float sPW[64];
    __shared__ __align__(16) float sPW0[64];
    __shared__ __align__(16) float sPB0[64];

    const int tid = threadIdx.x;
    self_prep(W0, b0, W1, W2, W3, W4, b1, b2, b3, b4, Wout,
              ldsA, sPB, sPW, sPW0, sPB0, tid);
    __syncthreads();

    const int lane = tid & 63;
    const int wv = tid >> 6;
    const int h = lane >> 5;
    const int lr = lane & 31;
    const int krow = blockIdx.x * 256 + wv * 32 + lr;   // node < NNODES

    const float xv = fmaf((float)krow, DELTA, XMIN);
    float r = mlp_eval(xv, lane, h, ldsA, sPB, sPW, sPW0, sPB0, bout[0]);
    if (h == 0) tab[krow] = r;
}

// ---------------- K2: gather / lerp ----------------------------------------
__device__ __forceinline__ float lerp1(float xc, const float* __restrict__ T) {
    float t = (xc - XMIN) * INVD;
    float kf = fminf(fmaxf(floorf(t), 0.0f), (float)(NINTERV - 1));
    int k = (int)kf;
    float node = fmaf(kf, DELTA, XMIN);          // bitwise == build's x_k
    float frac = (xc - node) * INVD;
    float t0 = T[k], t1 = T[k + 1];
    return fmaf(frac, t1 - t0, t0);
}

__global__ __launch_bounds__(256) void gather_lerp(
    const float* __restrict__ x, const float* __restrict__ T,
    float* __restrict__ out, int n)
{
    int i = blockIdx.x * 256 + threadIdx.x;
    int n4 = n >> 2;
    if (i < n4) {
        float4 v = ((const float4*)x)[i];
        vfloat4 r;
        r.x = lerp1(v.x, T);
        r.y = lerp1(v.y, T);
        r.z = lerp1(v.z, T);
        r.w = lerp1(v.w, T);
        __builtin_nontemporal_store(r, (vfloat4*)out + i);
    }
    if (blockIdx.x == 0 && threadIdx.x == 0) {   // scalar tail (n % 4)
        for (int j = n & ~3; j < n; ++j) out[j] = lerp1(x[j], T);
    }
}

// ---------------- fallback: direct per-row (ws too small; never expected) --
__global__ __launch_bounds__(512, 4) void mlp_direct(
    const float* __restrict__ x,
    const float* __restrict__ W0, const float* __restrict__ b0,
    const float* __restrict__ W1, const float* __restrict__ W2,
    const float* __restrict__ W3, const float* __restrict__ W4,
    const float* __restrict__ b1, const float* __restrict__ b2,
    const float* __restrict__ b3, const float* __restrict__ b4,
    const float* __restrict__ Wout, const float* __restrict__ bout,
    float* __restrict__ out, int n)
{
    __shared__ unsigned short ldsA[A_TOTAL];
    __shared__ __align__(16) float sPB[256];
    __shared__ __align__(16) float sPW[64];
    __shared__ __align__(16) float sPW0[64];
    __shared__ __align__(16) float sPB0[64];

    const int tid = threadIdx.x;
    self_prep(W0, b0, W1, W2, W3, W4, b1, b2, b3, b4, Wout,
              ldsA, sPB, sPW, sPW0, sPB0, tid);
    __syncthreads();

    const int lane = tid & 63;
    const int wv = tid >> 6;
    const int h = lane >> 5;
    const int lr = lane & 31;
    const int row = blockIdx.x * 256 + wv * 32 + lr;
    const float xv = (row < n) ? x[row] : 0.0f;

    float r = mlp_eval(xv, lane, h, ldsA, sPB, sPW, sPW0, sPB0, bout[0]);
    if (h == 0 && row < n) out[row] = r;
}

extern "C" void kernel_launch(void* const* d_in, const int* in_sizes, int n_in,
                              void* d_out, int out_size, void* d_ws, size_t ws_size,
                              hipStream_t stream) {
    const float* x    = (const float*)d_in[0];
    const float* W0   = (const float*)d_in[1];
    const float* b0   = (const float*)d_in[2];
    const float* W1   = (const float*)d_in[3];
    const float* b1   = (const float*)d_in[4];
    const float* W2   = (const float*)d_in[5];
    const float* b2   = (const float*)d_in[6];
    const float* W3   = (const float*)d_in[7];
    const float* b3   = (const float*)d_in[8];
    const float* W4   = (const float*)d_in[9];
    const float* b4   = (const float*)d_in[10];
    const float* Wout = (const float*)d_in[11];
    const float* bout = (const float*)d_in[12];
    float* out = (float*)d_out;

    int n = in_sizes[0];  // 2,097,152

    if (ws_size >= (size_t)WS_NEEDED) {
        float* tab = (float*)d_ws;
        build_table<<<NBUILD, 512, 0, stream>>>(W0, b0, W1, W2, W3, W4,
                                                b1, b2, b3, b4, Wout, bout, tab);
        int gblocks = (n / 4 + 255) / 256;
        gather_lerp<<<gblocks, 256, 0, stream>>>(x, tab, out, n);
    } else {
        mlp_direct<<<(n + 255) / 256, 512, 0, stream>>>(x, W0, b0, W1, W2, W3,
                                                        W4, b1, b2, b3, b4,
                                                        Wout, bout, out, n);
    }
}